// Round 3
// baseline (236.571 us; speedup 1.0000x reference)
//
#include <hip/hip_runtime.h>
#include <hip/hip_bf16.h>
#include <math.h>

#define NB 2
#define C 256
#define P 4096   // 64*64
#define EPS_F 1e-5f

typedef __attribute__((ext_vector_type(8))) short short8;
typedef __attribute__((ext_vector_type(4))) float f32x4;

// ---------------- K1: per-channel mean of featureT over n,h,w ----------------
__global__ void k_mean(const float* __restrict__ fT, float* __restrict__ mean) {
    int c = blockIdx.x;
    int t = threadIdx.x;
    const float* p0 = fT + (size_t)c * P;          // n=0
    const float* p1 = fT + (size_t)(C + c) * P;    // n=1
    float s = 0.f;
    for (int i = t; i < P; i += 256) s += p0[i] + p1[i];
    __shared__ float red[256];
    red[t] = s; __syncthreads();
    for (int o = 128; o > 0; o >>= 1) { if (t < o) red[t] += red[t + o]; __syncthreads(); }
    if (t == 0) mean[c] = red[0] * (1.f / 8192.f);
}

// ---------------- K2: per-pixel 1/||x - mean|| ----------------
__global__ void k_norm(const float* __restrict__ f, const float* __restrict__ mean,
                       float* __restrict__ rnorm) {
    __shared__ float mn[C];
    __shared__ float part[4][64];
    int t = threadIdx.x;
    mn[t] = mean[t];
    __syncthreads();
    int n = blockIdx.y;
    int p0 = blockIdx.x * 64;
    int pl = t & 63, cg = t >> 6;
    const float* base = f + (size_t)n * C * P + p0 + pl;
    float acc = 0.f;
    #pragma unroll 4
    for (int cc = 0; cc < 64; cc++) {
        int c = cg * 64 + cc;
        float v = base[(size_t)c * P] - mn[c];
        acc += v * v;
    }
    part[cg][pl] = acc;
    __syncthreads();
    if (t < 64) {
        float s = part[0][t] + part[1][t] + part[2][t] + part[3][t];
        rnorm[n * P + p0 + t] = rsqrtf(s);
    }
}

// ---------------- K3: transpose NCHW -> [n][p][c], center+scale, cast bf16 ----------------
__global__ void k_pack(const float* __restrict__ f, const float* __restrict__ mean,
                       const float* __restrict__ rnorm, __hip_bfloat16* __restrict__ out) {
    __shared__ float tile[64][65];
    int t = threadIdx.x;
    int n = blockIdx.z, c0 = blockIdx.y * 64, p0 = blockIdx.x * 64;
    const float* base = f + ((size_t)n * C + c0) * P + p0;
    #pragma unroll
    for (int i = 0; i < 16; i++) {
        int idx = t + 256 * i;
        int cc = idx >> 6, pp = idx & 63;
        tile[cc][pp] = base[(size_t)cc * P + pp] - mean[c0 + cc];
    }
    __syncthreads();
    #pragma unroll
    for (int i = 0; i < 16; i++) {
        int idx = t + 256 * i;
        int pp = idx >> 6, cc = idx & 63;
        float v = tile[cc][pp] * rnorm[n * P + p0 + pp];
        out[(size_t)(n * P + p0 + pp) * C + c0 + cc] = __float2bfloat16(v);
    }
}

// ---------------- shared GEMM tile: acc[m][nt] for one wave's 64x64 tile ----------------
__device__ __forceinline__ void gemm_tile(const __hip_bfloat16* __restrict__ A,
                                          const __hip_bfloat16* __restrict__ B,
                                          int qw, int pw, int lane, f32x4 acc[4][4]) {
    #pragma unroll
    for (int m = 0; m < 4; m++)
        #pragma unroll
        for (int nt = 0; nt < 4; nt++)
            acc[m][nt] = (f32x4){0.f, 0.f, 0.f, 0.f};
    int kbase = (lane >> 4) * 8;
    int rA = lane & 15;
    #pragma unroll
    for (int kk = 0; kk < 8; kk++) {
        short8 a[4], b[4];
        #pragma unroll
        for (int m = 0; m < 4; m++)
            a[m] = *reinterpret_cast<const short8*>(A + (size_t)(qw + m * 16 + rA) * C + kk * 32 + kbase);
        #pragma unroll
        for (int nt = 0; nt < 4; nt++)
            b[nt] = *reinterpret_cast<const short8*>(B + (size_t)(pw + nt * 16 + rA) * C + kk * 32 + kbase);
        #pragma unroll
        for (int m = 0; m < 4; m++)
            #pragma unroll
            for (int nt = 0; nt < 4; nt++)
                acc[m][nt] = __builtin_amdgcn_mfma_f32_16x16x32_bf16(a[m], b[nt], acc[m][nt], 0, 0, 0);
    }
}

// ---------------- GEMM pass A: row-max partials ----------------
__global__ __launch_bounds__(256) void k_gA(const __hip_bfloat16* __restrict__ TI,
                                            const __hip_bfloat16* __restrict__ TT,
                                            float* __restrict__ Mpart) {
    // grid: x = p-tile(32), y = q-tile(32), z = n(2); 4 waves 2x2 over 128x128
    int lane = threadIdx.x & 63, wid = threadIdx.x >> 6;
    int n = blockIdx.z;
    int qw = blockIdx.y * 128 + (wid >> 1) * 64;
    int pw = blockIdx.x * 128 + (wid & 1) * 64;
    const __hip_bfloat16* A = TI + (size_t)n * P * C;
    const __hip_bfloat16* B = TT + (size_t)n * P * C;
    f32x4 acc[4][4];
    gemm_tile(A, B, qw, pw, lane, acc);
    int pt = blockIdx.x * 2 + (wid & 1);
    #pragma unroll
    for (int m = 0; m < 4; m++) {
        f32x4 mx = acc[m][0];
        #pragma unroll
        for (int nt = 1; nt < 4; nt++)
            #pragma unroll
            for (int j = 0; j < 4; j++)
                mx[j] = fmaxf(mx[j], acc[m][nt][j]);
        #pragma unroll
        for (int j = 0; j < 4; j++)
            #pragma unroll
            for (int o = 1; o < 16; o <<= 1)
                mx[j] = fmaxf(mx[j], __shfl_xor(mx[j], o));
        if ((lane & 15) == 0) {
            int qbase = qw + m * 16 + (lane >> 4) * 4;
            #pragma unroll
            for (int j = 0; j < 4; j++)
                Mpart[((size_t)(n * P + qbase + j)) * 64 + pt] = mx[j];
        }
    }
}

// ---------------- reduce M -> t2, md ----------------
__global__ void k_redM(const float* __restrict__ Mpart, float* __restrict__ t2a,
                       float* __restrict__ mda) {
    int row = blockIdx.x * 256 + threadIdx.x;  // 0..8191
    const f32x4* src = (const f32x4*)(Mpart + (size_t)row * 64);
    float m = -1e30f;
    #pragma unroll
    for (int i = 0; i < 16; i++) {
        f32x4 v = src[i];
        m = fmaxf(m, fmaxf(fmaxf(v[0], v[1]), fmaxf(v[2], v[3])));
    }
    mda[row] = m;
    t2a[row] = 5.f / ((1.f - m) * 0.5f + EPS_F);
}

// ---------------- GEMM pass B: Z partials ----------------
__global__ __launch_bounds__(256) void k_gB(const __hip_bfloat16* __restrict__ TI,
                                            const __hip_bfloat16* __restrict__ TT,
                                            const float* __restrict__ t2a,
                                            const float* __restrict__ mda,
                                            float* __restrict__ Zpart) {
    int lane = threadIdx.x & 63, wid = threadIdx.x >> 6;
    int t = threadIdx.x;
    int n = blockIdx.z;
    __shared__ float st2[128], smd[128];
    if (t < 128) {
        st2[t] = t2a[n * P + blockIdx.y * 128 + t];
        smd[t] = mda[n * P + blockIdx.y * 128 + t];
    }
    __syncthreads();
    int qw = blockIdx.y * 128 + (wid >> 1) * 64;
    int pw = blockIdx.x * 128 + (wid & 1) * 64;
    const __hip_bfloat16* A = TI + (size_t)n * P * C;
    const __hip_bfloat16* B = TT + (size_t)n * P * C;
    f32x4 acc[4][4];
    gemm_tile(A, B, qw, pw, lane, acc);
    int pt = blockIdx.x * 2 + (wid & 1);
    int qloc0 = (wid >> 1) * 64;
    #pragma unroll
    for (int m = 0; m < 4; m++) {
        f32x4 z = (f32x4){0.f, 0.f, 0.f, 0.f};
        #pragma unroll
        for (int j = 0; j < 4; j++) {
            int ql = qloc0 + m * 16 + (lane >> 4) * 4 + j;
            float tt = st2[ql], mm = smd[ql];
            #pragma unroll
            for (int nt = 0; nt < 4; nt++)
                z[j] += __expf(tt * (acc[m][nt][j] - mm));
        }
        #pragma unroll
        for (int j = 0; j < 4; j++)
            #pragma unroll
            for (int o = 1; o < 16; o <<= 1)
                z[j] += __shfl_xor(z[j], o);
        if ((lane & 15) == 0) {
            int qbase = qw + m * 16 + (lane >> 4) * 4;
            #pragma unroll
            for (int j = 0; j < 4; j++)
                Zpart[((size_t)(n * P + qbase + j)) * 64 + pt] = z[j];
        }
    }
}

// ---------------- reduce Z -> rz ----------------
__global__ void k_redZ(const float* __restrict__ Zpart, float* __restrict__ rza) {
    int row = blockIdx.x * 256 + threadIdx.x;
    const f32x4* src = (const f32x4*)(Zpart + (size_t)row * 64);
    float z = 0.f;
    #pragma unroll
    for (int i = 0; i < 16; i++) {
        f32x4 v = src[i];
        z += v[0] + v[1] + v[2] + v[3];
    }
    rza[row] = 1.f / z;
}

// ---------------- GEMM pass C: column-max partials ----------------
__global__ __launch_bounds__(256) void k_gC(const __hip_bfloat16* __restrict__ TI,
                                            const __hip_bfloat16* __restrict__ TT,
                                            const float* __restrict__ t2a,
                                            const float* __restrict__ mda,
                                            const float* __restrict__ rza,
                                            float* __restrict__ Cpart) {
    int lane = threadIdx.x & 63, wid = threadIdx.x >> 6;
    int t = threadIdx.x;
    int n = blockIdx.z;
    __shared__ float st2[128], smd[128], srz[128];
    if (t < 128) {
        st2[t] = t2a[n * P + blockIdx.y * 128 + t];
        smd[t] = mda[n * P + blockIdx.y * 128 + t];
        srz[t] = rza[n * P + blockIdx.y * 128 + t];
    }
    __syncthreads();
    int qw = blockIdx.y * 128 + (wid >> 1) * 64;
    int pw = blockIdx.x * 128 + (wid & 1) * 64;
    const __hip_bfloat16* A = TI + (size_t)n * P * C;
    const __hip_bfloat16* B = TT + (size_t)n * P * C;
    f32x4 acc[4][4];
    gemm_tile(A, B, qw, pw, lane, acc);
    int qt2 = blockIdx.y * 2 + (wid >> 1);
    int qloc0 = (wid >> 1) * 64;
    #pragma unroll
    for (int nt = 0; nt < 4; nt++) {
        float c = 0.f;
        #pragma unroll
        for (int m = 0; m < 4; m++)
            #pragma unroll
            for (int j = 0; j < 4; j++) {
                int ql = qloc0 + m * 16 + (lane >> 4) * 4 + j;
                float v = __expf(st2[ql] * (acc[m][nt][j] - smd[ql])) * srz[ql];
                c = fmaxf(c, v);
            }
        c = fmaxf(c, __shfl_xor(c, 16));
        c = fmaxf(c, __shfl_xor(c, 32));
        if (lane < 16) {
            int col = pw + nt * 16 + lane;
            Cpart[((size_t)(n * P + col)) * 64 + qt2] = c;
        }
    }
}

// ---------------- reduce colmax partials -> colmax ----------------
__global__ void k_colred(const float* __restrict__ Cpart, float* __restrict__ colmax) {
    int p = blockIdx.x * 256 + threadIdx.x;  // flat n*P+p, 0..8191
    const f32x4* src = (const f32x4*)(Cpart + (size_t)p * 64);
    float c = 0.f;
    #pragma unroll
    for (int i = 0; i < 16; i++) {
        f32x4 v = src[i];
        c = fmaxf(c, fmaxf(fmaxf(v[0], v[1]), fmaxf(v[2], v[3])));
    }
    colmax[p] = c;
}

// ---------------- final: -log(mean_p colmax), mean over n ----------------
__global__ void k_final(const float* __restrict__ colmax, float* __restrict__ out) {
    __shared__ float red[256];
    int t = threadIdx.x;
    float cx[NB];
    for (int n = 0; n < NB; n++) {
        float s = 0.f;
        for (int i = t; i < P; i += 256) s += colmax[n * P + i];
        red[t] = s; __syncthreads();
        for (int o = 128; o > 0; o >>= 1) { if (t < o) red[t] += red[t + o]; __syncthreads(); }
        cx[n] = -logf(red[0] * (1.f / (float)P));
        __syncthreads();
    }
    if (t == 0) out[0] = 0.5f * (cx[0] + cx[1]);
}

extern "C" void kernel_launch(void* const* d_in, const int* in_sizes, int n_in,
                              void* d_out, int out_size, void* d_ws, size_t ws_size,
                              hipStream_t stream) {
    const float* fT = (const float*)d_in[0];   // featureT
    const float* fI = (const float*)d_in[1];   // featureI
    float* out = (float*)d_out;

    char* ws = (char*)d_ws;
    size_t off = 0;
    __hip_bfloat16* TI = (__hip_bfloat16*)(ws + off); off += 4194304;
    __hip_bfloat16* TT = (__hip_bfloat16*)(ws + off); off += 4194304;
    float* Mpart  = (float*)(ws + off); off += (size_t)NB * P * 64 * 4;  // 2 MiB
    float* Zpart  = (float*)(ws + off); off += (size_t)NB * P * 64 * 4;  // 2 MiB
    float* Cpart  = (float*)(ws + off); off += (size_t)NB * P * 64 * 4;  // 2 MiB
    float* mean   = (float*)(ws + off); off += 1024;
    float* rnormI = (float*)(ws + off); off += 32768;
    float* rnormT = (float*)(ws + off); off += 32768;
    float* t2a    = (float*)(ws + off); off += 32768;
    float* mda    = (float*)(ws + off); off += 32768;
    float* rza    = (float*)(ws + off); off += 32768;
    float* colmax = (float*)(ws + off); off += 32768;

    k_mean<<<256, 256, 0, stream>>>(fT, mean);
    k_norm<<<dim3(64, 2), 256, 0, stream>>>(fI, mean, rnormI);
    k_norm<<<dim3(64, 2), 256, 0, stream>>>(fT, mean, rnormT);
    k_pack<<<dim3(64, 4, 2), 256, 0, stream>>>(fI, mean, rnormI, TI);
    k_pack<<<dim3(64, 4, 2), 256, 0, stream>>>(fT, mean, rnormT, TT);
    k_gA<<<dim3(32, 32, 2), 256, 0, stream>>>(TI, TT, Mpart);
    k_redM<<<32, 256, 0, stream>>>(Mpart, t2a, mda);
    k_gB<<<dim3(32, 32, 2), 256, 0, stream>>>(TI, TT, t2a, mda, Zpart);
    k_redZ<<<32, 256, 0, stream>>>(Zpart, rza);
    k_gC<<<dim3(32, 32, 2), 256, 0, stream>>>(TI, TT, t2a, mda, rza, Cpart);
    k_colred<<<32, 256, 0, stream>>>(Cpart, colmax);
    k_final<<<1, 256, 0, stream>>>(colmax, out);
}

// Round 4
// 120.388 us; speedup vs baseline: 1.9651x; 1.9651x over previous
//
#include <hip/hip_runtime.h>
#include <hip/hip_bf16.h>
#include <math.h>

#define NB 2
#define C 256
#define P 4096   // 64*64
#define EPS_F 1e-5f

typedef __attribute__((ext_vector_type(8))) short short8;
typedef __attribute__((ext_vector_type(4))) float f32x4;

__device__ __forceinline__ float bf2f(unsigned short u) {
    union { unsigned int i; float f; } x;
    x.i = ((unsigned int)u) << 16;
    return x.f;
}

// ---------------- K1: per-channel mean of featureT over n,h,w ----------------
__global__ void k_mean(const float* __restrict__ fT, float* __restrict__ mean) {
    int c = blockIdx.x;
    int t = threadIdx.x;
    const float* p0 = fT + (size_t)c * P;          // n=0
    const float* p1 = fT + (size_t)(C + c) * P;    // n=1
    float s = 0.f;
    for (int i = t; i < P; i += 256) s += p0[i] + p1[i];
    __shared__ float red[256];
    red[t] = s; __syncthreads();
    for (int o = 128; o > 0; o >>= 1) { if (t < o) red[t] += red[t + o]; __syncthreads(); }
    if (t == 0) mean[c] = red[0] * (1.f / 8192.f);
}

// ---------------- K2: per-pixel 1/||x - mean|| ----------------
__global__ void k_norm(const float* __restrict__ f, const float* __restrict__ mean,
                       float* __restrict__ rnorm) {
    __shared__ float mn[C];
    __shared__ float part[4][64];
    int t = threadIdx.x;
    mn[t] = mean[t];
    __syncthreads();
    int n = blockIdx.y;
    int p0 = blockIdx.x * 64;
    int pl = t & 63, cg = t >> 6;
    const float* base = f + (size_t)n * C * P + p0 + pl;
    float acc = 0.f;
    #pragma unroll 4
    for (int cc = 0; cc < 64; cc++) {
        int c = cg * 64 + cc;
        float v = base[(size_t)c * P] - mn[c];
        acc += v * v;
    }
    part[cg][pl] = acc;
    __syncthreads();
    if (t < 64) {
        float s = part[0][t] + part[1][t] + part[2][t] + part[3][t];
        rnorm[n * P + p0 + t] = rsqrtf(s);
    }
}

// ---------------- K3: transpose NCHW -> [n][p][c], center+scale, cast bf16 ----------------
__global__ void k_pack(const float* __restrict__ f, const float* __restrict__ mean,
                       const float* __restrict__ rnorm, __hip_bfloat16* __restrict__ out) {
    __shared__ float tile[64][65];
    int t = threadIdx.x;
    int n = blockIdx.z, c0 = blockIdx.y * 64, p0 = blockIdx.x * 64;
    const float* base = f + ((size_t)n * C + c0) * P + p0;
    #pragma unroll
    for (int i = 0; i < 16; i++) {
        int idx = t + 256 * i;
        int cc = idx >> 6, pp = idx & 63;
        tile[cc][pp] = base[(size_t)cc * P + pp] - mean[c0 + cc];
    }
    __syncthreads();
    #pragma unroll
    for (int i = 0; i < 16; i++) {
        int idx = t + 256 * i;
        int pp = idx >> 6, cc = idx & 63;
        float v = tile[cc][pp] * rnorm[n * P + p0 + pp];
        out[(size_t)(n * P + p0 + pp) * C + c0 + cc] = __float2bfloat16(v);
    }
}

// ---------------- staging: one wave stages 32 rows x 32 cols (64B/row) of a tile ----------------
// LDS layout: linear [128][32] bf16 (64B rows). Source is pre-swizzled by
// cb ^= (row&3)<<4 so swizzled ds_reads below are 4-way instead of 8-way conflicted.
__device__ __forceinline__ void stage_tile(const __hip_bfloat16* __restrict__ gbase,
                                           __hip_bfloat16* lbuf, int kk, int wid, int lane) {
    #pragma unroll
    for (int j = 0; j < 2; j++) {
        int row = wid * 32 + j * 16 + (lane >> 2);
        int cb = (lane & 3) * 16;
        int scb = cb ^ ((row & 3) << 4);
        const char* gp = (const char*)gbase + (size_t)row * (C * 2) + kk * 64 + scb;
        char* lp = (char*)lbuf + (wid * 32 + j * 16) * 64;   // wave-uniform base
        __builtin_amdgcn_global_load_lds(
            (const __attribute__((address_space(1))) void*)gp,
            (__attribute__((address_space(3))) void*)lp, 16, 0, 0);
    }
}

__device__ __forceinline__ short8 ldfrag(const __hip_bfloat16* lbuf, int rloc, int kb) {
    int addr = rloc * 64 + (kb ^ ((rloc & 3) << 4));
    return *(const short8*)((const char*)lbuf + addr);
}

// ---------------- K4: fused GEMM: dist bf16 store + row-max partials ----------------
__global__ __launch_bounds__(256) void k_gemm(const __hip_bfloat16* __restrict__ TI,
                                              const __hip_bfloat16* __restrict__ TT,
                                              __hip_bfloat16* __restrict__ D,
                                              float* __restrict__ Mpart) {
    // grid: x = p-tile(32), y = q-tile(32), z = n(2); 4 waves 2x2 over 128x128, BK=32
    __shared__ __hip_bfloat16 lA[2][128 * 32];
    __shared__ __hip_bfloat16 lB[2][128 * 32];
    int lane = threadIdx.x & 63, wid = threadIdx.x >> 6;
    int wr = wid >> 1, wc = wid & 1;
    int n = blockIdx.z;
    const __hip_bfloat16* A = TI + ((size_t)n * P + blockIdx.y * 128) * C;
    const __hip_bfloat16* B = TT + ((size_t)n * P + blockIdx.x * 128) * C;

    f32x4 acc[4][4];
    #pragma unroll
    for (int m = 0; m < 4; m++)
        #pragma unroll
        for (int nt = 0; nt < 4; nt++)
            acc[m][nt] = (f32x4){0.f, 0.f, 0.f, 0.f};

    int rA = lane & 15;
    int kb = (lane >> 4) * 16;   // byte offset within 64B k-row

    stage_tile(A, lA[0], 0, wid, lane);
    stage_tile(B, lB[0], 0, wid, lane);
    __syncthreads();

    #pragma unroll
    for (int t = 0; t < 8; t++) {
        int cur = t & 1;
        if (t < 7) {
            stage_tile(A, lA[cur ^ 1], t + 1, wid, lane);
            stage_tile(B, lB[cur ^ 1], t + 1, wid, lane);
        }
        short8 a[4], b[4];
        #pragma unroll
        for (int m = 0; m < 4; m++)
            a[m] = ldfrag(lA[cur], wr * 64 + m * 16 + rA, kb);
        #pragma unroll
        for (int nt = 0; nt < 4; nt++)
            b[nt] = ldfrag(lB[cur], wc * 64 + nt * 16 + rA, kb);
        #pragma unroll
        for (int m = 0; m < 4; m++)
            #pragma unroll
            for (int nt = 0; nt < 4; nt++)
                acc[m][nt] = __builtin_amdgcn_mfma_f32_16x16x32_bf16(a[m], b[nt], acc[m][nt], 0, 0, 0);
        __syncthreads();
    }

    // epilogue 1: bf16 dist store
    int qb = blockIdx.y * 128 + wr * 64;
    int pb = blockIdx.x * 128 + wc * 64;
    int rj = (lane >> 4) * 4, cl = lane & 15;
    __hip_bfloat16* Dn = D + (size_t)n * P * P;
    #pragma unroll
    for (int m = 0; m < 4; m++)
        #pragma unroll
        for (int nt = 0; nt < 4; nt++)
            #pragma unroll
            for (int j = 0; j < 4; j++)
                Dn[(size_t)(qb + m * 16 + rj + j) * P + pb + nt * 16 + cl] =
                    __float2bfloat16(acc[m][nt][j]);

    // epilogue 2: row-max partials (exact, fp32)
    int pt = blockIdx.x * 2 + wc;
    #pragma unroll
    for (int m = 0; m < 4; m++) {
        f32x4 mx = acc[m][0];
        #pragma unroll
        for (int nt = 1; nt < 4; nt++)
            #pragma unroll
            for (int j = 0; j < 4; j++)
                mx[j] = fmaxf(mx[j], acc[m][nt][j]);
        #pragma unroll
        for (int j = 0; j < 4; j++)
            #pragma unroll
            for (int o = 1; o < 16; o <<= 1)
                mx[j] = fmaxf(mx[j], __shfl_xor(mx[j], o));
        if ((lane & 15) == 0) {
            int qbase = qb + m * 16 + (lane >> 4) * 4;
            #pragma unroll
            for (int j = 0; j < 4; j++)
                Mpart[((size_t)(n * P + qbase + j)) * 64 + pt] = mx[j];
        }
    }
}

// ---------------- reduce M -> t2, md ----------------
__global__ void k_redM(const float* __restrict__ Mpart, float* __restrict__ t2a,
                       float* __restrict__ mda) {
    int row = blockIdx.x * 256 + threadIdx.x;  // 0..8191
    const f32x4* src = (const f32x4*)(Mpart + (size_t)row * 64);
    float m = -1e30f;
    #pragma unroll
    for (int i = 0; i < 16; i++) {
        f32x4 v = src[i];
        m = fmaxf(m, fmaxf(fmaxf(v[0], v[1]), fmaxf(v[2], v[3])));
    }
    mda[row] = m;
    t2a[row] = 5.f / ((1.f - m) * 0.5f + EPS_F);
}

// ---------------- K5: per-row Z (one block per row, bf16 dist) ----------------
__global__ __launch_bounds__(256) void k_rowz(const __hip_bfloat16* __restrict__ D,
                                              const float* __restrict__ t2a,
                                              const float* __restrict__ mda,
                                              float* __restrict__ rza) {
    int row = blockIdx.x;   // flat n*P+q, 0..8191
    int t = threadIdx.x;
    float t2 = t2a[row], md = mda[row];
    const short8* src = (const short8*)(D + (size_t)row * P);
    float z = 0.f;
    #pragma unroll
    for (int i = 0; i < 2; i++) {
        short8 v = src[t + 256 * i];
        #pragma unroll
        for (int j = 0; j < 8; j++)
            z += __expf(t2 * (bf2f((unsigned short)v[j]) - md));
    }
    #pragma unroll
    for (int o = 32; o > 0; o >>= 1) z += __shfl_xor(z, o);
    __shared__ float redz[4];
    int lane = t & 63, w = t >> 6;
    if (lane == 0) redz[w] = z;
    __syncthreads();
    if (t == 0) rza[row] = 1.f / (redz[0] + redz[1] + redz[2] + redz[3]);
}

// ---------------- K6: colmax partials over q-segments ----------------
__global__ __launch_bounds__(256) void k_colmax(const __hip_bfloat16* __restrict__ D,
                                                const float* __restrict__ t2a,
                                                const float* __restrict__ mda,
                                                const float* __restrict__ rza,
                                                float* __restrict__ Cpart) {
    // grid: x = p-chunk(16), y = q-seg(16), z = n(2); block 256
    __shared__ float st2[256], smd[256], srz[256];
    int t = threadIdx.x;
    int n = blockIdx.z, q0 = blockIdx.y * 256, p = blockIdx.x * 256 + t;
    st2[t] = t2a[n * P + q0 + t];
    smd[t] = mda[n * P + q0 + t];
    srz[t] = rza[n * P + q0 + t];
    __syncthreads();
    const __hip_bfloat16* base = D + ((size_t)n * P + q0) * P + p;
    float local = 0.f;
    for (int j = 0; j < 256; j++) {
        float d = bf2f(*(const unsigned short*)(base + (size_t)j * P));
        float v = __expf(st2[j] * (d - smd[j])) * srz[j];
        local = fmaxf(local, v);
    }
    Cpart[((size_t)(n * P + p)) * 16 + blockIdx.y] = local;
}

// ---------------- reduce colmax partials ----------------
__global__ void k_colred(const float* __restrict__ Cpart, float* __restrict__ colmax) {
    int p = blockIdx.x * 256 + threadIdx.x;  // flat n*P+p, 0..8191
    const f32x4* src = (const f32x4*)(Cpart + (size_t)p * 16);
    float c = 0.f;
    #pragma unroll
    for (int i = 0; i < 4; i++) {
        f32x4 v = src[i];
        c = fmaxf(c, fmaxf(fmaxf(v[0], v[1]), fmaxf(v[2], v[3])));
    }
    colmax[p] = c;
}

// ---------------- final: -log(mean_p colmax), mean over n ----------------
__global__ void k_final(const float* __restrict__ colmax, float* __restrict__ out) {
    __shared__ float red[256];
    int t = threadIdx.x;
    float cx[NB];
    for (int n = 0; n < NB; n++) {
        float s = 0.f;
        for (int i = t; i < P; i += 256) s += colmax[n * P + i];
        red[t] = s; __syncthreads();
        for (int o = 128; o > 0; o >>= 1) { if (t < o) red[t] += red[t + o]; __syncthreads(); }
        cx[n] = -logf(red[0] * (1.f / (float)P));
        __syncthreads();
    }
    if (t == 0) out[0] = 0.5f * (cx[0] + cx[1]);
}

extern "C" void kernel_launch(void* const* d_in, const int* in_sizes, int n_in,
                              void* d_out, int out_size, void* d_ws, size_t ws_size,
                              hipStream_t stream) {
    const float* fT = (const float*)d_in[0];   // featureT
    const float* fI = (const float*)d_in[1];   // featureI
    float* out = (float*)d_out;

    char* ws = (char*)d_ws;
    size_t off = 0;
    __hip_bfloat16* TI = (__hip_bfloat16*)(ws + off); off += 4194304;
    __hip_bfloat16* TT = (__hip_bfloat16*)(ws + off); off += 4194304;
    __hip_bfloat16* D  = (__hip_bfloat16*)(ws + off); off += (size_t)NB * P * P * 2;  // 67 MiB
    float* Mpart  = (float*)(ws + off); off += (size_t)NB * P * 64 * 4;               // 2 MiB
    float* Cpart  = (float*)(ws + off); off += (size_t)NB * P * 16 * 4;               // 512 KiB
    float* mean   = (float*)(ws + off); off += 1024;
    float* rnormI = (float*)(ws + off); off += 32768;
    float* rnormT = (float*)(ws + off); off += 32768;
    float* t2a    = (float*)(ws + off); off += 32768;
    float* mda    = (float*)(ws + off); off += 32768;
    float* rza    = (float*)(ws + off); off += 32768;
    float* colmax = (float*)(ws + off); off += 32768;

    k_mean<<<256, 256, 0, stream>>>(fT, mean);
    k_norm<<<dim3(64, 2), 256, 0, stream>>>(fI, mean, rnormI);
    k_norm<<<dim3(64, 2), 256, 0, stream>>>(fT, mean, rnormT);
    k_pack<<<dim3(64, 4, 2), 256, 0, stream>>>(fI, mean, rnormI, TI);
    k_pack<<<dim3(64, 4, 2), 256, 0, stream>>>(fT, mean, rnormT, TT);
    k_gemm<<<dim3(32, 32, 2), 256, 0, stream>>>(TI, TT, D, Mpart);
    k_redM<<<32, 256, 0, stream>>>(Mpart, t2a, mda);
    k_rowz<<<8192, 256, 0, stream>>>(D, t2a, mda, rza);
    k_colmax<<<dim3(16, 16, 2), 256, 0, stream>>>(D, t2a, mda, rza, Cpart);
    k_colred<<<32, 256, 0, stream>>>(Cpart, colmax);
    k_final<<<1, 256, 0, stream>>>(colmax, out);
}